// Round 4
// baseline (632.559 us; speedup 1.0000x reference)
//
#include <hip/hip_runtime.h>
#include <hip/hip_fp16.h>

// ---------------- problem constants ----------------
#define NI 3
#define NS 32
#define CHN 512
#define OH 23
#define P2 529          // 23*23
#define NP 50784        // NI*NS*P2
#define UV 484          // 22*22
#define WSZ 262144      // NS*CHN*16

typedef unsigned int uint32;
typedef unsigned short u16;
typedef _Float16 h2 __attribute__((ext_vector_type(2)));

// ---------------- workspace layout (bytes) ----------------
// featT layout: [snT(96)][cb4(4)][uv(484)][c(128)] f16 — c-pair u32 slot l in a
// 128-c block holds channels (128*cb4 + 2l, +1).
#define OFF_FEATT 0UL           // 23,789,568 halves = 47,579,136 B
#define OFF_LABEL 47579136UL    // 50784 f32
#define OFF_S0    47782272UL    // 50784 f32 (scores ping)
#define OFF_S1    47985408UL    // 50784 f32 (scores pong)
#define OFF_SGRAW 48188544UL    // 50784 f32 (A*wg raw)
#define OFF_WG    48391680UL    // 262144 f32
#define OFF_WGF16 49440256UL    // 262144 f16, layout [s][tap][c]
#define OFF_W0F16 49964544UL    // 262144 f16, layout [s][tap][c]
#define OFF_PART  50488832UL    // partial-sum arrays (float), ~32 KB

// partial-array float indices — each slot written by exactly ONE block; NO atomics.
#define P_DEN   0       // [5][32][27] : per-(t,s,pg) sum sg^2 partials
#define P_NUM   4320    // [5][32][8]  : per-(t,s,chunk) sum wg^2 partials
#define P_LOSS  5600    // [5][32]     : per-(t,s) residual-loss partials
#define P_WSQ0  5760    // [32]        : sum w0^2 per s
#define P_WSQA  5792    // [4][32][8]  : sum w_t^2 partials, t=1..4
#define P_WSQ5  6816    // [1024]      : sum w5^2 per block
#define P_L5    7840    // [199]       : final loss per block

__device__ __forceinline__ float waveSum(float v) {
#pragma unroll
  for (int o = 32; o > 0; o >>= 1) v += __shfl_xor(v, o, 64);
  return v;
}

__device__ __forceinline__ float dot2f(uint32 a, uint32 b, float c) {
#if __has_builtin(__builtin_amdgcn_fdot2)
  return __builtin_amdgcn_fdot2(__builtin_bit_cast(h2, a), __builtin_bit_cast(h2, b), c, false);
#else
  h2 av = __builtin_bit_cast(h2, a), bv = __builtin_bit_cast(h2, b);
  return c + (float)av[0] * (float)bv[0] + (float)av[1] * (float)bv[1];
#endif
}

__device__ __forceinline__ float alphaFor(const float* __restrict__ part, int t, int s,
                                          float reg) {
  const float* np_ = part + P_NUM + (size_t)(t * NS + s) * 8;
  const float* dp_ = part + P_DEN + (size_t)(t * NS + s) * 27;
  float nu = 0.f, de = 0.f;
#pragma unroll
  for (int i = 0; i < 8; ++i) nu += np_[i];
#pragma unroll
  for (int i = 0; i < 27; ++i) de += dp_[i];
  return nu / fmaxf(de + reg * nu, 1e-8f);
}

// ---------------- setup: coalesced feat->f16 transpose (small tiles), w, label --------
// transpose block = (snT, cb of 64 ch, uvq of 121 uv): LDS 64x121 f32 = 31 KB
// grid = 96*8*4 = 3072 (transpose) + 32 (w) + 199 (label) = 3303 blocks x 256
__global__ __launch_bounds__(256) void k_setup(const float* __restrict__ feat,
                                               const float* __restrict__ w0,
                                               const float* __restrict__ bb,
                                               u16* __restrict__ featT,
                                               u16* __restrict__ w0f16,
                                               float* __restrict__ wmaster,
                                               float* __restrict__ label,
                                               float* __restrict__ part) {
  __shared__ float ldsT[7744];  // [64 ch][121 uv], pitch 121 (odd -> 2-way max)
  __shared__ float sred[4];
  int b = blockIdx.x, tid = threadIdx.x;
  if (b < 3072) {
    int snT = b >> 5, r5 = b & 31;
    int cb = r5 >> 2, uvq = r5 & 3;  // 64-ch group, 121-uv quarter
    int s = snT / 3, n = snT % 3;
    const float* fsrc =
        feat + ((size_t)n * NS + s) * CHN * UV + (size_t)(cb * 64) * UV + uvq * 121;
    // read: 64 rows x 121 floats, coalesced along uv
#pragma unroll
    for (int it = 0; it < 31; ++it) {
      int idx = it * 256 + tid;
      if (idx < 7744) {
        int r = (unsigned)idx / 121u;
        int j = idx - r * 121;
        ldsT[idx] = fsrc[r * 484 + j];
      }
    }
    __syncthreads();
    // write: 121 uv x 32 c-pair u32, coalesced along c-pair (k)
    uint32* dstb = (uint32*)featT +
                   ((size_t)(snT * 4 + (cb >> 1)) * UV + uvq * 121) * 64 + (cb & 1) * 32;
#pragma unroll
    for (int it = 0; it < 16; ++it) {
      int o = it * 256 + tid;
      if (o < 3872) {
        int uv = o >> 5, k = o & 31;
        float f0 = ldsT[(2 * k) * 121 + uv];
        float f1 = ldsT[(2 * k + 1) * 121 + uv];
        uint32 pk = (uint32)__half_as_ushort(__float2half(f0)) |
                    ((uint32)__half_as_ushort(__float2half(f1)) << 16);
        dstb[(size_t)uv * 64 + k] = pk;
      }
    }
  } else if (b < 3104) {
    int s = b - 3072;
    for (int i = tid; i < 8192; i += 256) {
      int tap = i >> 9, c = i & 511;
      w0f16[(size_t)s * 8192 + i] =
          __half_as_ushort(__float2half(w0[(size_t)s * 8192 + c * 16 + tap]));
    }
    float sq = 0.f;
    for (int i = tid; i < 8192; i += 256) {
      float v = w0[(size_t)s * 8192 + i];
      wmaster[(size_t)s * 8192 + i] = v;
      sq += v * v;
    }
    sq = waveSum(sq);
    if ((tid & 63) == 0) sred[tid >> 6] = sq;
    __syncthreads();
    if (tid == 0) part[P_WSQ0 + s] = sred[0] + sred[1] + sred[2] + sred[3];
  } else {
    int p = (b - 3104) * 256 + tid;
    if (p < NP) {
      int nsid = p / P2, rem = p % P2;
      int i = rem / OH, j = rem % OH;
      const float* bp = bb + (size_t)nsid * 4;
      float cr = (bp[1] + 0.5f * bp[3]) * 0.0625f;
      float cc = (bp[0] + 0.5f * bp[2]) * 0.0625f;
      float dy = (float)i - cr, dx = (float)j - cc;
      label[p] = __expf(-0.5f * (dy * dy + dx * dx));
    }
  }
}

// ---------------- forward conv: out = A * w  (w f16 [s][tap][c]) ----------------
// grid = 864 = 8 xcd x 4 sq x 27 pg; XCD-affine. Lane loads uint2 (2 c-pairs):
// half-wave covers one cb4 block, 2 outer iterations cover all 512 channels.
__global__ __launch_bounds__(256) void k_conv_fwd(const u16* __restrict__ featT,
                                                  const u16* __restrict__ wf16,
                                                  float* __restrict__ outbuf, int t,
                                                  float* __restrict__ part) {
  __shared__ uint32 w_lds[4096];  // 16 taps x 256 c-pairs
  __shared__ float dred[4];
  int tid = threadIdx.x;
  int b = blockIdx.x;
  int xcd = b & 7, g = b >> 3;
  int s = xcd + 8 * (g & 3), pg = g >> 2;
  const uint32* wsrc = (const uint32*)(wf16 + (size_t)s * 8192);
  for (int i = tid; i < 4096; i += 256) w_lds[i] = wsrc[i];
  __syncthreads();
  int wave = tid >> 6, lane = tid & 63;
  int half = lane >> 5, l2 = lane & 31;
  int p = pg * 4 + wave;  // 0..107
  int n = p / 36, q = p % 36;
  int y0 = (q / 6) * 4, x0 = (q % 6) * 4;
  const uint32* fb = (const uint32*)featT + (size_t)(s * 3 + n) * 4 * UV * 64;
  float av[16];
#pragma unroll
  for (int i = 0; i < 16; ++i) av[i] = 0.f;
  for (int cc2 = 0; cc2 < 2; ++cc2) {
    int cb = cc2 * 2 + half;  // per-lane cb4 block
    const uint2* fcb = (const uint2*)(fb + (size_t)cb * UV * 64) + l2;
    uint2 F[49];
#pragma unroll
    for (int ri = 0; ri < 7; ++ri) {
      int ur = y0 - 2 + ri;
#pragma unroll
      for (int ci = 0; ci < 7; ++ci) {
        int vc = x0 - 2 + ci;
        bool ok = ((unsigned)ur < 22u) && ((unsigned)vc < 22u);
        uint2 z;
        z.x = 0u;
        z.y = 0u;
        F[ri * 7 + ci] = ok ? fcb[(size_t)(ur * 22 + vc) * 32] : z;
      }
    }
    uint2 wv[16];
#pragma unroll
    for (int tap = 0; tap < 16; ++tap)
      wv[tap] = ((const uint2*)w_lds)[tap * 128 + cb * 32 + l2];
#pragma unroll
    for (int oy = 0; oy < 4; ++oy)
#pragma unroll
      for (int ox = 0; ox < 4; ++ox) {
        float a = av[oy * 4 + ox];
#pragma unroll
        for (int ky = 0; ky < 4; ++ky)
#pragma unroll
          for (int kx = 0; kx < 4; ++kx) {
            uint2 f = F[(oy + ky) * 7 + ox + kx];
            uint2 w = wv[ky * 4 + kx];
            a = dot2f(f.x, w.x, a);
            a = dot2f(f.y, w.y, a);
          }
        av[oy * 4 + ox] = a;
      }
  }
#pragma unroll
  for (int i = 0; i < 16; ++i) av[i] = waveSum(av[i]);
  float val = 0.f;
#pragma unroll
  for (int i = 0; i < 16; ++i) val = (lane == i) ? av[i] : val;
  int yy = y0 + (lane >> 2), xx = x0 + (lane & 3);
  if (lane < 16 && yy < OH && xx < OH)
    outbuf[(size_t)(n * NS + s) * P2 + yy * OH + xx] = val;
  if (t >= 0) {
    if (lane == 0) {
      float dsum = 0.f;
#pragma unroll
      for (int i = 0; i < 16; ++i) {
        int y2 = y0 + (i >> 2), x2 = x0 + (i & 3);
        if (y2 < OH && x2 < OH) dsum += av[i] * av[i];
      }
      dred[wave] = dsum;
    }
    __syncthreads();
    if (tid == 0)
      part[P_DEN + (size_t)(t * NS + s) * 27 + pg] =
          (dred[0] + dred[1] + dred[2] + dred[3]) * (1.0f / 3.0f);
  }
}

// ---------------- adjoint + fused alpha/w-update/scores-recurrence/loss ----------------
// grid = 32 s * 8 c-chunks = 256 blocks x 768
__global__ __launch_bounds__(768) void k_adjoint(
    int t, const u16* __restrict__ featT, const float* __restrict__ label,
    const float* __restrict__ scores_old, float* __restrict__ scores_new,
    const float* __restrict__ sgraw, float* __restrict__ wg, u16* __restrict__ wgf16,
    float* __restrict__ wmaster, float* __restrict__ part, const float* __restrict__ lsl,
    const float* __restrict__ fr) {
  __shared__ float r_lds[1950];   // [3][25][26], zero-padded residuals * sw^2
  __shared__ float red[12288];    // [32 j=(cj,ky,kx)][12 m][32 cp]
  __shared__ float lred[12];
  __shared__ float nred2[2], wred2[2];
  int tid = threadIdx.x;
  int s = blockIdx.x >> 3, chunk = blockIdx.x & 7;
  int c0 = chunk * 64;
  int cp = tid & 31, tg1 = (tid >> 5) & 1, m = tid >> 6;
  int n = m >> 2, uq = m & 3;
  int u0 = (uq * 22) >> 2, u1 = ((uq + 1) * 22) >> 2;
  float step = __expf(lsl[0]);
  float frv = fr[0];
  float reg = fmaxf(frv * frv, 1e-6f);
  float alpha_p = (t >= 1) ? alphaFor(part, t - 1, s, reg) : 0.f;
  for (int i = tid; i < 1950; i += 768) r_lds[i] = 0.f;
  __syncthreads();
  float lsum = 0.f;
  for (int pl = tid; pl < 1587; pl += 768) {
    int nn = pl / P2, rem = pl % P2;
    int y = rem / OH, x = rem % OH;
    size_t gp = (size_t)(nn * NS + s) * P2 + rem;
    float S = scores_old[gp];
    if (t >= 1) S -= step * alpha_p * sgraw[gp];  // scores recurrence
    float d = S - label[gp];
    r_lds[nn * 650 + (y + 1) * 26 + (x + 1)] = d * (1.0f / 3.0f);  // sw^2 * resid
    if (chunk == 0) {
      if (t >= 1) scores_new[gp] = S;
      lsum += d * d;
    }
  }
  lsum = waveSum(lsum);
  if ((tid & 63) == 0) lred[tid >> 6] = lsum;
  __syncthreads();
  if (chunk == 0 && tid == 0) {
    float L = 0.f;
#pragma unroll
    for (int i = 0; i < 12; ++i) L += lred[i];
    part[P_LOSS + t * NS + s] = L * (1.0f / 3.0f);
  }
  const uint32* fb = (const uint32*)featT +
                     ((size_t)(s * 3 + n) * 4 + (chunk >> 1)) * UV * 64 +
                     (chunk & 1) * 32 + cp;
  float ac[16];  // [cj2][kyi2][kx4]
#pragma unroll
  for (int i = 0; i < 16; ++i) ac[i] = 0.f;
  const float* rbase = r_lds + n * 650;
  for (int u = u0; u < u1; ++u) {
    const float* rA = rbase + (u + 3 - tg1) * 26;  // ky = tg1
    const float* rB = rbase + (u + 1 - tg1) * 26;  // ky = tg1+2
    const uint32* fp_ = fb + (size_t)u * 22 * 64;
#pragma unroll
    for (int v = 0; v < 22; ++v) {
      uint32 fv = fp_[(size_t)v * 64];
      h2 hv = __builtin_bit_cast(h2, fv);
      float f0 = (float)hv[0], f1 = (float)hv[1];
#pragma unroll
      for (int kx = 0; kx < 4; ++kx) {
        float ra = rA[v + 3 - kx];
        float rb_ = rB[v + 3 - kx];
        ac[0 + kx] = fmaf(f0, ra, ac[0 + kx]);
        ac[4 + kx] = fmaf(f0, rb_, ac[4 + kx]);
        ac[8 + kx] = fmaf(f1, ra, ac[8 + kx]);
        ac[12 + kx] = fmaf(f1, rb_, ac[12 + kx]);
      }
    }
  }
#pragma unroll
  for (int cj = 0; cj < 2; ++cj)
#pragma unroll
    for (int kyi = 0; kyi < 2; ++kyi)
#pragma unroll
      for (int kx = 0; kx < 4; ++kx) {
        int ky = tg1 + 2 * kyi;
        int j = (cj * 4 + ky) * 4 + kx;
        red[(j * 12 + m) * 32 + cp] = ac[cj * 8 + kyi * 4 + kx];
      }
  __syncthreads();
  if (tid < 128) {  // owners: 64 c x 16 taps of this chunk, 8 each
    int ocp = tid & 31, ky = tid >> 5;
    float wsq_part = 0.f, num_part = 0.f;
#pragma unroll
    for (int jj = 0; jj < 8; ++jj) {
      int cj = jj >> 2, kx = jj & 3;
      int j = (cj * 4 + ky) * 4 + kx;
      float dg = 0.f;
#pragma unroll
      for (int mm = 0; mm < 12; ++mm) dg += red[(j * 12 + mm) * 32 + ocp];
      int c = c0 + 2 * ocp + cj;
      int tap = ky * 4 + kx;
      size_t widx = (size_t)s * 8192 + (size_t)c * 16 + tap;
      float wold = wmaster[widx];
      float wnew = wold;
      if (t >= 1) {
        wnew = wold - step * alpha_p * wg[widx];
        wmaster[widx] = wnew;
      }
      float wgn = dg + reg * wnew;
      wg[widx] = wgn;
      wgf16[(size_t)s * 8192 + tap * 512 + c] = __half_as_ushort(__float2half(wgn));
      wsq_part += wnew * wnew;
      num_part += wgn * wgn;
    }
    wsq_part = waveSum(wsq_part);
    num_part = waveSum(num_part);
    if ((tid & 63) == 0) {
      nred2[tid >> 6] = num_part;
      wred2[tid >> 6] = wsq_part;
    }
  }
  __syncthreads();
  if (tid == 0) {
    part[P_NUM + (size_t)(t * NS + s) * 8 + chunk] = nred2[0] + nred2[1];
    if (t >= 1) part[P_WSQA + (size_t)((t - 1) * NS + s) * 8 + chunk] = wred2[0] + wred2[1];
  }
}

// ---------------- final: w5 update + final residual loss parts ----------------
__global__ void k_final(float* __restrict__ wmaster, const float* __restrict__ wg,
                        const float* __restrict__ scores4, const float* __restrict__ sgraw,
                        const float* __restrict__ label, float* __restrict__ part,
                        const float* __restrict__ lsl, const float* __restrict__ fr) {
  __shared__ float alpha_s[32];
  __shared__ float red4[4];
  int b = blockIdx.x, tid = threadIdx.x;
  float step = __expf(lsl[0]);
  float frv = fr[0];
  float reg = fmaxf(frv * frv, 1e-6f);
  if (tid < 32) alpha_s[tid] = alphaFor(part, 4, tid, reg);
  __syncthreads();
  if (b < 1024) {
    int idx = b * 256 + tid;  // 1024*256 == 262144 exactly
    int s = idx >> 13;        // uniform per block
    float w5 = wmaster[idx] - step * alpha_s[s] * wg[idx];
    wmaster[idx] = w5;
    float sq = waveSum(w5 * w5);
    if ((tid & 63) == 0) red4[tid >> 6] = sq;
    __syncthreads();
    if (tid == 0) part[P_WSQ5 + b] = red4[0] + red4[1] + red4[2] + red4[3];
  } else {
    int p = (b - 1024) * 256 + tid;
    float contrib = 0.f;
    if (p < NP) {
      int nsid = p / P2;
      int s = nsid & 31;  // nsid = n*NS + s
      float s5 = scores4[p] - step * alpha_s[s] * sgraw[p];
      float d = s5 - label[p];
      contrib = d * d;
    }
    contrib = waveSum(contrib);
    if ((tid & 63) == 0) red4[tid >> 6] = contrib;
    __syncthreads();
    if (tid == 0)
      part[P_L5 + (b - 1024)] = (red4[0] + red4[1] + red4[2] + red4[3]) * (1.0f / 3.0f);
  }
}

// ---------------- losses: deterministic sums of all partials ----------------
__global__ void k_losses(float* __restrict__ out_losses, const float* __restrict__ part,
                         const float* __restrict__ fr) {
  __shared__ float red[8];
  int tid = threadIdx.x;  // 256
  float frv = fr[0];
  float reg = fmaxf(frv * frv, 1e-6f);
  float v5 = 0.f;
  for (int i = tid; i < 1024; i += 256) v5 += part[P_WSQ5 + i];
  v5 = waveSum(v5);
  if ((tid & 63) == 0) red[tid >> 6] = v5;
  __syncthreads();
  float wsq5 = red[0] + red[1] + red[2] + red[3];
  float l5 = 0.f;
  for (int i = tid; i < 199; i += 256) l5 += part[P_L5 + i];
  l5 = waveSum(l5);
  if ((tid & 63) == 0) red[4 + (tid >> 6)] = l5;
  __syncthreads();
  float loss5 = red[4] + red[5] + red[6] + red[7];
  if (tid < 5) {
    int t = tid;
    float ls = 0.f;
    for (int i = 0; i < 32; ++i) ls += part[P_LOSS + t * NS + i];
    float ws_ = 0.f;
    if (t == 0) {
      for (int i = 0; i < 32; ++i) ws_ += part[P_WSQ0 + i];
    } else {
      for (int i = 0; i < 256; ++i) ws_ += part[P_WSQA + (t - 1) * 256 + i];
    }
    out_losses[t] = (ls + reg * ws_) * (1.0f / 32.0f);
  }
  if (tid == 5) out_losses[5] = (loss5 + reg * wsq5) * (1.0f / 32.0f);
}

// ---------------- launch ----------------
extern "C" void kernel_launch(void* const* d_in, const int* in_sizes, int n_in,
                              void* d_out, int out_size, void* d_ws, size_t ws_size,
                              hipStream_t stream) {
  const float* w0 = (const float*)d_in[0];
  const float* feat = (const float*)d_in[1];
  const float* bb = (const float*)d_in[2];
  const float* lsl = (const float*)d_in[3];
  const float* fr = (const float*)d_in[4];
  float* out = (float*)d_out;
  char* ws = (char*)d_ws;
  u16* featT = (u16*)(ws + OFF_FEATT);
  float* label = (float*)(ws + OFF_LABEL);
  float* s0 = (float*)(ws + OFF_S0);
  float* s1 = (float*)(ws + OFF_S1);
  float* sgraw = (float*)(ws + OFF_SGRAW);
  float* wg = (float*)(ws + OFF_WG);
  u16* wgf16 = (u16*)(ws + OFF_WGF16);
  u16* w0f16 = (u16*)(ws + OFF_W0F16);
  float* part = (float*)(ws + OFF_PART);

  k_setup<<<3303, 256, 0, stream>>>(feat, w0, bb, featT, w0f16, out, label, part);
  // initial scores_0 = A * w0
  k_conv_fwd<<<864, 256, 0, stream>>>(featT, w0f16, s0, -1, part);
  float* sbuf[2] = {s0, s1};
  for (int t = 0; t < 5; ++t) {
    const float* so = (t == 0) ? s0 : sbuf[(t - 1) & 1];
    float* sn = sbuf[t & 1];
    k_adjoint<<<256, 768, 0, stream>>>(t, featT, label, so, sn, sgraw, wg, wgf16, out, part,
                                       lsl, fr);
    k_conv_fwd<<<864, 256, 0, stream>>>(featT, wgf16, sgraw, t, part);
  }
  // scores_4 lives in s0 after t=4
  k_final<<<1223, 256, 0, stream>>>(out, wg, s0, sgraw, label, part, lsl, fr);
  k_losses<<<1, 256, 0, stream>>>(out + WSZ, part, fr);
}

// Round 5
// 397.743 us; speedup vs baseline: 1.5904x; 1.5904x over previous
//
#include <hip/hip_runtime.h>
#include <hip/hip_fp16.h>

// ---------------- problem constants ----------------
#define NI 3
#define NS 32
#define CHN 512
#define OH 23
#define P2 529          // 23*23
#define NP 50784        // NI*NS*P2
#define UV 484          // 22*22
#define WSZ 262144      // NS*CHN*16

typedef unsigned int uint32;
typedef unsigned short u16;
typedef _Float16 h2 __attribute__((ext_vector_type(2)));
typedef _Float16 f16x8 __attribute__((ext_vector_type(8)));
typedef float f32x4 __attribute__((ext_vector_type(4)));

// ---------------- workspace layout (bytes) ----------------
// featT layout: [snT(96)][cb4(4)][uv(484)][c(128)] f16, snT = s*3+n
#define OFF_FEATT 0UL           // 23,789,568 halves = 47,579,136 B
#define OFF_LABEL 47579136UL    // 50784 f32
#define OFF_S0    47782272UL    // 50784 f32 (scores ping)
#define OFF_S1    47985408UL    // 50784 f32 (scores pong)
#define OFF_SGRAW 48188544UL    // 50784 f32 (A*wg raw)
#define OFF_WG    48391680UL    // 262144 f32
#define OFF_WGF16 49440256UL    // 262144 f16, layout [s][tap][c]
#define OFF_W0F16 49964544UL    // 262144 f16, layout [s][tap][c]
#define OFF_PART  50488832UL    // partial-sum arrays (float), ~32 KB

// partial-array float indices — each slot written by exactly ONE block; NO atomics.
#define P_DEN   0       // [5][32][3]  : per-(t,s,n) sum sg^2 partials
#define P_NUM   4320    // [5][32][8]  : per-(t,s,chunk) sum wg^2 partials
#define P_LOSS  5600    // [5][32]     : per-(t,s) residual-loss partials
#define P_WSQ0  5760    // [32]        : sum w0^2 per s
#define P_WSQA  5792    // [4][32][8]  : sum w_t^2 partials, t=1..4
#define P_WSQ5  6816    // [1024]      : sum w5^2 per block
#define P_L5    7840    // [199]       : final loss per block

__device__ __forceinline__ float waveSum(float v) {
#pragma unroll
  for (int o = 32; o > 0; o >>= 1) v += __shfl_xor(v, o, 64);
  return v;
}

__device__ __forceinline__ float alphaFor(const float* __restrict__ part, int t, int s,
                                          float reg) {
  const float* np_ = part + P_NUM + (size_t)(t * NS + s) * 8;
  const float* dp_ = part + P_DEN + (size_t)(t * NS + s) * 3;
  float nu = 0.f;
#pragma unroll
  for (int i = 0; i < 8; ++i) nu += np_[i];
  float de = dp_[0] + dp_[1] + dp_[2];
  return nu / fmaxf(de + reg * nu, 1e-8f);
}

// ---------------- setup: coalesced feat->f16 transpose (small tiles), w, label --------
// transpose block = (snT, cb of 64 ch, uvq of 121 uv): LDS 64x121 f32 = 31 KB
// grid = 96*8*4 = 3072 (transpose) + 32 (w) + 199 (label) = 3303 blocks x 256
__global__ __launch_bounds__(256) void k_setup(const float* __restrict__ feat,
                                               const float* __restrict__ w0,
                                               const float* __restrict__ bb,
                                               u16* __restrict__ featT,
                                               u16* __restrict__ w0f16,
                                               float* __restrict__ wmaster,
                                               float* __restrict__ label,
                                               float* __restrict__ part) {
  __shared__ float ldsT[7744];  // [64 ch][121 uv], pitch 121
  __shared__ float sred[4];
  int b = blockIdx.x, tid = threadIdx.x;
  if (b < 3072) {
    int snT = b >> 5, r5 = b & 31;
    int cb = r5 >> 2, uvq = r5 & 3;  // 64-ch group, 121-uv quarter
    int s = snT / 3, n = snT % 3;
    const float* fsrc =
        feat + ((size_t)n * NS + s) * CHN * UV + (size_t)(cb * 64) * UV + uvq * 121;
#pragma unroll
    for (int it = 0; it < 31; ++it) {
      int idx = it * 256 + tid;
      if (idx < 7744) {
        int r = (unsigned)idx / 121u;
        int j = idx - r * 121;
        ldsT[idx] = fsrc[r * 484 + j];
      }
    }
    __syncthreads();
    uint32* dstb = (uint32*)featT +
                   ((size_t)(snT * 4 + (cb >> 1)) * UV + uvq * 121) * 64 + (cb & 1) * 32;
#pragma unroll
    for (int it = 0; it < 16; ++it) {
      int o = it * 256 + tid;
      if (o < 3872) {
        int uv = o >> 5, k = o & 31;
        float f0 = ldsT[(2 * k) * 121 + uv];
        float f1 = ldsT[(2 * k + 1) * 121 + uv];
        uint32 pk = (uint32)__half_as_ushort(__float2half(f0)) |
                    ((uint32)__half_as_ushort(__float2half(f1)) << 16);
        dstb[(size_t)uv * 64 + k] = pk;
      }
    }
  } else if (b < 3104) {
    int s = b - 3072;
    for (int i = tid; i < 8192; i += 256) {
      int tap = i >> 9, c = i & 511;
      w0f16[(size_t)s * 8192 + i] =
          __half_as_ushort(__float2half(w0[(size_t)s * 8192 + c * 16 + tap]));
    }
    float sq = 0.f;
    for (int i = tid; i < 8192; i += 256) {
      float v = w0[(size_t)s * 8192 + i];
      wmaster[(size_t)s * 8192 + i] = v;
      sq += v * v;
    }
    sq = waveSum(sq);
    if ((tid & 63) == 0) sred[tid >> 6] = sq;
    __syncthreads();
    if (tid == 0) part[P_WSQ0 + s] = sred[0] + sred[1] + sred[2] + sred[3];
  } else {
    int p = (b - 3104) * 256 + tid;
    if (p < NP) {
      int nsid = p / P2, rem = p % P2;
      int i = rem / OH, j = rem % OH;
      const float* bp = bb + (size_t)nsid * 4;
      float cr = (bp[1] + 0.5f * bp[3]) * 0.0625f;
      float cc = (bp[0] + 0.5f * bp[2]) * 0.0625f;
      float dy = (float)i - cr, dx = (float)j - cc;
      label[p] = __expf(-0.5f * (dy * dy + dx * dx));
    }
  }
}

// ---------------- forward conv via MFMA ----------------
// Per (s,n): G[uv,tap] = featT[uv,c] . w[c,tap]  (484x16x512 GEMM, 16x16x32 f16 MFMA)
// then scores[y,x] = sum_{ky,kx} G[(y+ky-2)*22+(x+kx-2), ky*4+kx]  (LDS gather).
// grid = 96 blocks (snT) x 1024 threads (16 waves; wave w owns M-tiles w and w+16).
__global__ __launch_bounds__(1024) void k_conv_fwd(const u16* __restrict__ featT,
                                                   const u16* __restrict__ wf16,
                                                   float* __restrict__ outbuf, int t,
                                                   float* __restrict__ part) {
  __shared__ uint32 w_lds[16 * 260];  // [tap][c-pair], pitch 260 (bank-stagger)
  __shared__ float G[496 * 17];       // [uv-row][tap], pitch 17
  __shared__ float dred[16];
  int tid = threadIdx.x;
  int snT = blockIdx.x;
  int s = snT / 3, n = snT - s * 3;
  const uint32* wsrc = (const uint32*)(wf16 + (size_t)s * 8192);
  for (int i = tid; i < 4096; i += 1024) {
    int tap = i >> 8, p = i & 255;
    w_lds[tap * 260 + p] = wsrc[i];
  }
  __syncthreads();
  int wave = tid >> 6, lane = tid & 63;
  int q = lane >> 4, m16 = lane & 15;
  int t0 = wave, t1 = (wave < 15) ? wave + 16 : wave;
  f32x4 acc0 = {0.f, 0.f, 0.f, 0.f}, acc1 = {0.f, 0.f, 0.f, 0.f};
  size_t base = (size_t)snT * 4 * UV * 128;
  size_t row0 = (size_t)(t0 * 16 + m16) * 128;
  size_t row1 = (size_t)(t1 * 16 + m16) * 128;
#pragma unroll
  for (int step = 0; step < 16; ++step) {
    int cb = step >> 2, cin = (step & 3) * 32;
    size_t cbase = base + (size_t)cb * UV * 128 + cin + q * 8;
    f16x8 a0 = *(const f16x8*)(featT + cbase + row0);
    f16x8 a1 = *(const f16x8*)(featT + cbase + row1);
    uint4 bw = *(const uint4*)&w_lds[m16 * 260 + step * 16 + q * 4];
    f16x8 bf = __builtin_bit_cast(f16x8, bw);
    acc0 = __builtin_amdgcn_mfma_f32_16x16x32_f16(a0, bf, acc0, 0, 0, 0);
    acc1 = __builtin_amdgcn_mfma_f32_16x16x32_f16(a1, bf, acc1, 0, 0, 0);
  }
  // D layout: col=lane&15 (tap), row=(lane>>4)*4+reg (uv within tile)
#pragma unroll
  for (int r = 0; r < 4; ++r) G[(t0 * 16 + q * 4 + r) * 17 + m16] = acc0[r];
  if (wave < 15) {
#pragma unroll
    for (int r = 0; r < 4; ++r) G[(t1 * 16 + q * 4 + r) * 17 + m16] = acc1[r];
  }
  __syncthreads();
  float dsq = 0.f;
  int p = tid;
  if (p < P2) {
    int y = p / 23, x = p - y * 23;
    float val = 0.f;
#pragma unroll
    for (int ky = 0; ky < 4; ++ky) {
      int u = y + ky - 2;
      if ((unsigned)u < 22u) {
#pragma unroll
        for (int kx = 0; kx < 4; ++kx) {
          int v = x + kx - 2;
          if ((unsigned)v < 22u) val += G[(u * 22 + v) * 17 + ky * 4 + kx];
        }
      }
    }
    outbuf[(size_t)(n * NS + s) * P2 + p] = val;
    dsq = val * val;
  }
  if (t >= 0) {  // t uniform
    dsq = waveSum(dsq);
    if (lane == 0) dred[wave] = dsq;
    __syncthreads();
    if (tid == 0) {
      float dsum = 0.f;
#pragma unroll
      for (int i = 0; i < 16; ++i) dsum += dred[i];
      part[P_DEN + (size_t)(t * NS + s) * 3 + n] = dsum * (1.0f / 3.0f);
    }
  }
}

// ---------------- adjoint + fused alpha/w-update/scores-recurrence/loss ----------------
// grid = 32 s * 8 c-chunks = 256 blocks x 768
__global__ __launch_bounds__(768) void k_adjoint(
    int t, const u16* __restrict__ featT, const float* __restrict__ label,
    const float* __restrict__ scores_old, float* __restrict__ scores_new,
    const float* __restrict__ sgraw, float* __restrict__ wg, u16* __restrict__ wgf16,
    float* __restrict__ wmaster, float* __restrict__ part, const float* __restrict__ lsl,
    const float* __restrict__ fr) {
  __shared__ float r_lds[1950];   // [3][25][26], zero-padded residuals * sw^2
  __shared__ float red[12288];    // [32 j=(cj,ky,kx)][12 m][32 cp]
  __shared__ float lred[12];
  __shared__ float nred2[2], wred2[2];
  int tid = threadIdx.x;
  int s = blockIdx.x >> 3, chunk = blockIdx.x & 7;
  int c0 = chunk * 64;
  int cp = tid & 31, tg1 = (tid >> 5) & 1, m = tid >> 6;
  int n = m >> 2, uq = m & 3;
  int u0 = (uq * 22) >> 2, u1 = ((uq + 1) * 22) >> 2;
  float step = __expf(lsl[0]);
  float frv = fr[0];
  float reg = fmaxf(frv * frv, 1e-6f);
  float alpha_p = (t >= 1) ? alphaFor(part, t - 1, s, reg) : 0.f;
  for (int i = tid; i < 1950; i += 768) r_lds[i] = 0.f;
  __syncthreads();
  float lsum = 0.f;
  for (int pl = tid; pl < 1587; pl += 768) {
    int nn = pl / P2, rem = pl % P2;
    int y = rem / OH, x = rem % OH;
    size_t gp = (size_t)(nn * NS + s) * P2 + rem;
    float S = scores_old[gp];
    if (t >= 1) S -= step * alpha_p * sgraw[gp];  // scores recurrence
    float d = S - label[gp];
    r_lds[nn * 650 + (y + 1) * 26 + (x + 1)] = d * (1.0f / 3.0f);  // sw^2 * resid
    if (chunk == 0) {
      if (t >= 1) scores_new[gp] = S;
      lsum += d * d;
    }
  }
  lsum = waveSum(lsum);
  if ((tid & 63) == 0) lred[tid >> 6] = lsum;
  __syncthreads();
  if (chunk == 0 && tid == 0) {
    float L = 0.f;
#pragma unroll
    for (int i = 0; i < 12; ++i) L += lred[i];
    part[P_LOSS + t * NS + s] = L * (1.0f / 3.0f);
  }
  const uint32* fb = (const uint32*)featT +
                     ((size_t)(s * 3 + n) * 4 + (chunk >> 1)) * UV * 64 +
                     (chunk & 1) * 32 + cp;
  float ac[16];  // [cj2][kyi2][kx4]
#pragma unroll
  for (int i = 0; i < 16; ++i) ac[i] = 0.f;
  const float* rbase = r_lds + n * 650;
  for (int u = u0; u < u1; ++u) {
    const float* rA = rbase + (u + 3 - tg1) * 26;  // ky = tg1
    const float* rB = rbase + (u + 1 - tg1) * 26;  // ky = tg1+2
    const uint32* fp_ = fb + (size_t)u * 22 * 64;
#pragma unroll
    for (int v = 0; v < 22; ++v) {
      uint32 fv = fp_[(size_t)v * 64];
      h2 hv = __builtin_bit_cast(h2, fv);
      float f0 = (float)hv[0], f1 = (float)hv[1];
#pragma unroll
      for (int kx = 0; kx < 4; ++kx) {
        float ra = rA[v + 3 - kx];
        float rb_ = rB[v + 3 - kx];
        ac[0 + kx] = fmaf(f0, ra, ac[0 + kx]);
        ac[4 + kx] = fmaf(f0, rb_, ac[4 + kx]);
        ac[8 + kx] = fmaf(f1, ra, ac[8 + kx]);
        ac[12 + kx] = fmaf(f1, rb_, ac[12 + kx]);
      }
    }
  }
#pragma unroll
  for (int cj = 0; cj < 2; ++cj)
#pragma unroll
    for (int kyi = 0; kyi < 2; ++kyi)
#pragma unroll
      for (int kx = 0; kx < 4; ++kx) {
        int ky = tg1 + 2 * kyi;
        int j = (cj * 4 + ky) * 4 + kx;
        red[(j * 12 + m) * 32 + cp] = ac[cj * 8 + kyi * 4 + kx];
      }
  __syncthreads();
  if (tid < 128) {  // owners: 64 c x 16 taps of this chunk, 8 each
    int ocp = tid & 31, ky = tid >> 5;
    float wsq_part = 0.f, num_part = 0.f;
#pragma unroll
    for (int jj = 0; jj < 8; ++jj) {
      int cj = jj >> 2, kx = jj & 3;
      int j = (cj * 4 + ky) * 4 + kx;
      float dg = 0.f;
#pragma unroll
      for (int mm = 0; mm < 12; ++mm) dg += red[(j * 12 + mm) * 32 + ocp];
      int c = c0 + 2 * ocp + cj;
      int tap = ky * 4 + kx;
      size_t widx = (size_t)s * 8192 + (size_t)c * 16 + tap;
      float wold = wmaster[widx];
      float wnew = wold;
      if (t >= 1) {
        wnew = wold - step * alpha_p * wg[widx];
        wmaster[widx] = wnew;
      }
      float wgn = dg + reg * wnew;
      wg[widx] = wgn;
      wgf16[(size_t)s * 8192 + tap * 512 + c] = __half_as_ushort(__float2half(wgn));
      wsq_part += wnew * wnew;
      num_part += wgn * wgn;
    }
    wsq_part = waveSum(wsq_part);
    num_part = waveSum(num_part);
    if ((tid & 63) == 0) {
      nred2[tid >> 6] = num_part;
      wred2[tid >> 6] = wsq_part;
    }
  }
  __syncthreads();
  if (tid == 0) {
    part[P_NUM + (size_t)(t * NS + s) * 8 + chunk] = nred2[0] + nred2[1];
    if (t >= 1) part[P_WSQA + (size_t)((t - 1) * NS + s) * 8 + chunk] = wred2[0] + wred2[1];
  }
}

// ---------------- final: w5 update + final residual loss parts ----------------
__global__ void k_final(float* __restrict__ wmaster, const float* __restrict__ wg,
                        const float* __restrict__ scores4, const float* __restrict__ sgraw,
                        const float* __restrict__ label, float* __restrict__ part,
                        const float* __restrict__ lsl, const float* __restrict__ fr) {
  __shared__ float alpha_s[32];
  __shared__ float red4[4];
  int b = blockIdx.x, tid = threadIdx.x;
  float step = __expf(lsl[0]);
  float frv = fr[0];
  float reg = fmaxf(frv * frv, 1e-6f);
  if (tid < 32) alpha_s[tid] = alphaFor(part, 4, tid, reg);
  __syncthreads();
  if (b < 1024) {
    int idx = b * 256 + tid;  // 1024*256 == 262144 exactly
    int s = idx >> 13;        // uniform per block
    float w5 = wmaster[idx] - step * alpha_s[s] * wg[idx];
    wmaster[idx] = w5;
    float sq = waveSum(w5 * w5);
    if ((tid & 63) == 0) red4[tid >> 6] = sq;
    __syncthreads();
    if (tid == 0) part[P_WSQ5 + b] = red4[0] + red4[1] + red4[2] + red4[3];
  } else {
    int p = (b - 1024) * 256 + tid;
    float contrib = 0.f;
    if (p < NP) {
      int nsid = p / P2;
      int s = nsid & 31;  // nsid = n*NS + s
      float s5 = scores4[p] - step * alpha_s[s] * sgraw[p];
      float d = s5 - label[p];
      contrib = d * d;
    }
    contrib = waveSum(contrib);
    if ((tid & 63) == 0) red4[tid >> 6] = contrib;
    __syncthreads();
    if (tid == 0)
      part[P_L5 + (b - 1024)] = (red4[0] + red4[1] + red4[2] + red4[3]) * (1.0f / 3.0f);
  }
}

// ---------------- losses: deterministic sums of all partials ----------------
__global__ void k_losses(float* __restrict__ out_losses, const float* __restrict__ part,
                         const float* __restrict__ fr) {
  __shared__ float red[8];
  int tid = threadIdx.x;  // 256
  float frv = fr[0];
  float reg = fmaxf(frv * frv, 1e-6f);
  float v5 = 0.f;
  for (int i = tid; i < 1024; i += 256) v5 += part[P_WSQ5 + i];
  v5 = waveSum(v5);
  if ((tid & 63) == 0) red[tid >> 6] = v5;
  __syncthreads();
  float wsq5 = red[0] + red[1] + red[2] + red[3];
  float l5 = 0.f;
  for (int i = tid; i < 199; i += 256) l5 += part[P_L5 + i];
  l5 = waveSum(l5);
  if ((tid & 63) == 0) red[4 + (tid >> 6)] = l5;
  __syncthreads();
  float loss5 = red[4] + red[5] + red[6] + red[7];
  if (tid < 5) {
    int t = tid;
    float ls = 0.f;
    for (int i = 0; i < 32; ++i) ls += part[P_LOSS + t * NS + i];
    float ws_ = 0.f;
    if (t == 0) {
      for (int i = 0; i < 32; ++i) ws_ += part[P_WSQ0 + i];
    } else {
      for (int i = 0; i < 256; ++i) ws_ += part[P_WSQA + (t - 1) * 256 + i];
    }
    out_losses[t] = (ls + reg * ws_) * (1.0f / 32.0f);
  }
  if (tid == 5) out_losses[5] = (loss5 + reg * wsq5) * (1.0f / 32.0f);
}

// ---------------- launch ----------------
extern "C" void kernel_launch(void* const* d_in, const int* in_sizes, int n_in,
                              void* d_out, int out_size, void* d_ws, size_t ws_size,
                              hipStream_t stream) {
  const float* w0 = (const float*)d_in[0];
  const float* feat = (const float*)d_in[1];
  const float* bb = (const float*)d_in[2];
  const float* lsl = (const float*)d_in[3];
  const float* fr = (const float*)d_in[4];
  float* out = (float*)d_out;
  char* ws = (char*)d_ws;
  u16* featT = (u16*)(ws + OFF_FEATT);
  float* label = (float*)(ws + OFF_LABEL);
  float* s0 = (float*)(ws + OFF_S0);
  float* s1 = (float*)(ws + OFF_S1);
  float* sgraw = (float*)(ws + OFF_SGRAW);
  float* wg = (float*)(ws + OFF_WG);
  u16* wgf16 = (u16*)(ws + OFF_WGF16);
  u16* w0f16 = (u16*)(ws + OFF_W0F16);
  float* part = (float*)(ws + OFF_PART);

  k_setup<<<3303, 256, 0, stream>>>(feat, w0, bb, featT, w0f16, out, label, part);
  // initial scores_0 = A * w0
  k_conv_fwd<<<96, 1024, 0, stream>>>(featT, w0f16, s0, -1, part);
  float* sbuf[2] = {s0, s1};
  for (int t = 0; t < 5; ++t) {
    const float* so = (t == 0) ? s0 : sbuf[(t - 1) & 1];
    float* sn = sbuf[t & 1];
    k_adjoint<<<256, 768, 0, stream>>>(t, featT, label, so, sn, sgraw, wg, wgf16, out, part,
                                       lsl, fr);
    k_conv_fwd<<<96, 1024, 0, stream>>>(featT, wgf16, sgraw, t, part);
  }
  // scores_4 lives in s0 after t=4
  k_final<<<1223, 256, 0, stream>>>(out, wg, s0, sgraw, label, part, lsl, fr);
  k_losses<<<1, 256, 0, stream>>>(out + WSZ, part, fr);
}